// Round 6
// baseline (1493.016 us; speedup 1.0000x reference)
//
#include <hip/hip_runtime.h>
#include <stdint.h>
#include <stddef.h>

typedef __bf16 bf16;
typedef __bf16 bf16x4 __attribute__((ext_vector_type(4)));
typedef __bf16 bf16x8 __attribute__((ext_vector_type(8)));
typedef float f32x4 __attribute__((ext_vector_type(4)));

#define MFMA(a, b, c) __builtin_amdgcn_mfma_f32_16x16x32_bf16(a, b, c, 0, 0, 0)

static constexpr int kB = 4, kN = 4096, kC = 1024, kH = 16, kD = 64;
static constexpr int kM = kB * kN;   // 16384 token rows
static constexpr int kK = 1024;      // contraction dim for both GEMMs
static constexpr int kQKVN = 3072;

// async 16B global->LDS (direct-to-LDS DMA; dest = wave-uniform base + lane*16)
__device__ __forceinline__ void cp16(const void* g, void* l) {
  __builtin_amdgcn_global_load_lds(
      (const __attribute__((address_space(1))) void*)g,
      (__attribute__((address_space(3))) void*)l, 16, 0, 0);
}

// fp32 -> bf16 elementwise convert, 4 elems/thread
__global__ __launch_bounds__(256) void cvt_bf16(const float* __restrict__ src,
                                                bf16* __restrict__ dst, int n4) {
  const int i = blockIdx.x * 256 + threadIdx.x;
  if (i < n4) {
    const float4 v = ((const float4*)src)[i];
    bf16x4 o = {(bf16)v.x, (bf16)v.y, (bf16)v.z, (bf16)v.w};
    *(bf16x4*)&dst[4 * i] = o;
  }
}

// rope on 8 consecutive d-elements (4 aligned pairs)
__device__ __forceinline__ bf16x8 rope8(bf16x8 t, bf16x8 f) {
  bf16x8 o;
#pragma unroll
  for (int p = 0; p < 4; ++p) {
    float t0 = (float)t[2 * p], t1 = (float)t[2 * p + 1];
    float f0 = (float)f[2 * p], f1 = (float)f[2 * p + 1];
    o[2 * p]     = (bf16)(t0 * f0 - t1 * f1);
    o[2 * p + 1] = (bf16)(t1 * f0 + t0 * f1);
  }
  return o;
}

// C[m][n] = sum_k A[m][k] * Bw[n][k] (+ bias[n]).  A: kM x kK, Bw: NOUT x kK (bf16 row-major).
//
// TWO-PHASE schedule with RING-2 LDS => 2 blocks/CU co-residency:
//   256x256 tile, BK=32, 8 waves (2M x 4N, each 128x64 out), ring of 2 LDS K-tile
//   buffers (32 KB each = 64 KB => 2 blocks/CU, 16 waves: one block's MFMA window
//   covers the other block's read/drain window — cross-block overlap needs no
//   barriers, unlike intra-block waves which are lockstep at 4 barriers/K-tile).
//   tile t, phase 0: { ds_read A frags + B cols 0..31 of t ; stageA/B(t+1) [8 cp16,
//                      issue-early] ; s_barrier ; setprio(1) 16 MFMA setprio(0) ; s_barrier }
//   tile t, phase 1: { ds_read B cols 32..63 ; s_waitcnt vmcnt(0) [t+1 confirmed —
//                      issued a full MFMA window ago, L2 latency covered] ; s_barrier ;
//                      setprio(1) 16 MFMA setprio(0) ; s_barrier }
//   WAR: stage(t+1) rewrites buf[(t+1)&1], last read at tile t-1; those reads precede
//   the end-of-(t-1) barrier; stage issues after it. Visibility: ph1's vmcnt(0)+barrier
//   publishes t+1 before its first read (t+1 ph0).
//   LDS layout per tile: [row 0..255][4 slots x 16B] (one row = one 64B cache line);
//   slot s holds k-chunk kb = s ^ ((row>>1)&3): coalesced cp16 (4 lanes = 1 full
//   line) and conflict-free swizzled b128 fragment reads (XOR term lane-constant).
template <int NOUT, bool BIAS, typename OutT>
__global__ __launch_bounds__(512, 4) void gemm_bt(const bf16* __restrict__ A,
                                                  const bf16* __restrict__ Bw,
                                                  const float* __restrict__ bias,
                                                  OutT* __restrict__ Cout) {
  __shared__ unsigned short As[2][256 * 32];  // 16 KB per buf: [row][slot*8 + e]
  __shared__ unsigned short Bs[2][256 * 32];
  const int tid = threadIdx.x;
  const int wave = tid >> 6, lane = tid & 63;
  const int q4 = lane >> 4, l16 = lane & 15;
  const int wr = wave >> 2, wc = wave & 3;

  const int nwg = gridDim.x * gridDim.y;
  int bid = blockIdx.y * gridDim.x + blockIdx.x;
  bid = (bid & 7) * (nwg >> 3) + (bid >> 3);
  const int bx = bid % gridDim.x, by = bid / gridDim.x;
  const int n0 = bx * 256, m0 = by * 256;

  constexpr int NT = kK / 32;  // 32 K-tiles

  f32x4 acc[8][4] = {};

  auto stageA = [&](int kt) {
    const int buf = kt & 1;
#pragma unroll
    for (int i = 0; i < 2; ++i) {
      const int c = i * 512 + tid;            // 0..1023, linear LDS dest (c*16 B)
      const int row = c >> 2, s = c & 3;      // 4 lanes per row = one 64B line
      const int kb = s ^ ((row >> 1) & 3);    // inverse-swizzled source chunk
      cp16(A + (size_t)(m0 + row) * kK + kt * 32 + kb * 8, &As[buf][c * 8]);
    }
  };
  auto stageB = [&](int kt) {
    const int buf = kt & 1;
#pragma unroll
    for (int i = 0; i < 2; ++i) {
      const int c = i * 512 + tid;
      const int row = c >> 2, s = c & 3;
      const int kb = s ^ ((row >> 1) & 3);
      cp16(Bw + (size_t)(n0 + row) * kK + kt * 32 + kb * 8, &Bs[buf][c * 8]);
    }
  };

  // prologue: stage tile 0, drain, publish
  stageA(0); stageB(0);
  asm volatile("s_waitcnt vmcnt(0)\n\ts_barrier" ::: "memory");

  const int slot8 = (q4 ^ ((l16 >> 1) & 3)) * 8;
  const int arow = wr * 128 + l16;  // + i*16
  const int bcol = wc * 64 + l16;   // + j*16

  for (int t = 0; t < NT; ++t) {
    const int rb = t & 1;
    // ---- phase 0: A frags + B cols 0..31 of tile t; issue stage(t+1) early
    bf16x8 a[8], b0, b1;
#pragma unroll
    for (int i = 0; i < 8; ++i)
      a[i] = *(const bf16x8*)&As[rb][(arow + i * 16) * 32 + slot8];
    b0 = *(const bf16x8*)&Bs[rb][bcol * 32 + slot8];
    b1 = *(const bf16x8*)&Bs[rb][(bcol + 16) * 32 + slot8];
    if (t + 1 < NT) { stageA(t + 1); stageB(t + 1); }
    asm volatile("s_barrier" ::: "memory");
    __builtin_amdgcn_s_setprio(1);
#pragma unroll
    for (int i = 0; i < 8; ++i) {
      acc[i][0] = MFMA(a[i], b0, acc[i][0]);
      acc[i][1] = MFMA(a[i], b1, acc[i][1]);
    }
    __builtin_amdgcn_s_setprio(0);
    asm volatile("s_barrier" ::: "memory");

    // ---- phase 1: B cols 32..63; drain tile t+1's stage (issued ~1.5 phases ago)
    bf16x8 b2 = *(const bf16x8*)&Bs[rb][(bcol + 32) * 32 + slot8];
    bf16x8 b3 = *(const bf16x8*)&Bs[rb][(bcol + 48) * 32 + slot8];
    asm volatile("s_waitcnt vmcnt(0)\n\ts_barrier" ::: "memory");
    __builtin_amdgcn_s_setprio(1);
#pragma unroll
    for (int i = 0; i < 8; ++i) {
      acc[i][2] = MFMA(a[i], b2, acc[i][2]);
      acc[i][3] = MFMA(a[i], b3, acc[i][3]);
    }
    __builtin_amdgcn_s_setprio(0);
    asm volatile("s_barrier" ::: "memory");
  }

  // epilogue: C/D layout col=lane&15, row=(lane>>4)*4+reg
#pragma unroll
  for (int i = 0; i < 8; ++i) {
    const int rowb = m0 + wr * 128 + i * 16 + q4 * 4;
#pragma unroll
    for (int j = 0; j < 4; ++j) {
      const int col = n0 + wc * 64 + j * 16 + l16;
      const float bv = BIAS ? bias[col] : 0.0f;
#pragma unroll
      for (int r = 0; r < 4; ++r)
        Cout[(size_t)(rowb + r) * NOUT + col] = (OutT)(acc[i][j][r] + bv);
    }
  }
}

// One block per (b,h,w) window. 4 waves x 64 q-rows, q-groups of 16 rows.
// SWAPPED-OPERAND flash attention: S^T = mfma(K, Q) so each lane owns the
// token axis (softmax axis) for one query column q=l16:
//  - softmax: 31 in-lane ops + 2 shfl_xor (vs 32 bpermutes)
//  - P round-trip: lane's 4 values = 4 consecutive tokens -> packed b64 writes
//    into pT[q][tok] (XOR-swizzled, conflict-free), b128 reads as PV A-frag
//  - V transpose staging XOR-swizzled: 16-way write conflict -> conflict-free
__global__ __launch_bounds__(256) void attn_win(const bf16* __restrict__ qkv,
                                                const bf16* __restrict__ freqs,
                                                bf16* __restrict__ ob) {
  __shared__ unsigned short k8[8 * 128 * 8];  // [dblk][tok][8]  16 KB (roped K)
  __shared__ unsigned short v8[16 * 64 * 8];  // [tokblk][d^swz][8] 16 KB (V^T)
  __shared__ unsigned short pT[4][16 * 128];  // per wave [q:16][tok:128] 4 KB

  const int bid = blockIdx.x;
  const int w = bid & 15, h = (bid >> 4) & 15, b = bid >> 8;
  const int n0 = w * 256;
  const int tid = threadIdx.x;
  const int wave = tid >> 6, lane = tid & 63;
  const int q4 = lane >> 4, l16 = lane & 15;
  const float scale = 0.125f;  // D^-0.5
  const int swz = (l16 & 7) << 4;  // byte XOR for pT (bits 4-6)
  char* const pw = (char*)&pT[wave][0];

  // q fragments with rope, hoisted (B-frag: col=l16=q, k=(q4)*8+e, s picks d-half)
  bf16x8 qf[4][2];
#pragma unroll
  for (int g = 0; g < 4; ++g) {
    const int n = n0 + wave * 64 + g * 16 + l16;
    const bf16* qrow = qkv + (size_t)(b * kN + n) * kQKVN + h * kD;
    const bf16* frow = freqs + (size_t)n * kD;
#pragma unroll
    for (int s = 0; s < 2; ++s) {
      const int d0 = s * 32 + q4 * 8;
      qf[g][s] = rope8(*(const bf16x8*)(qrow + d0), *(const bf16x8*)(frow + d0));
    }
  }

  f32x4 O[4][4] = {};       // [group][d-tile]; rows q=q4*4+r, cols d=l16+16*jd
  float mrow[4], lrow[4];   // per-lane stats for q = g*16 + l16
#pragma unroll
  for (int g = 0; g < 4; ++g) { mrow[g] = -3.0e38f; lrow[g] = 0.0f; }

  for (int c = 0; c < 2; ++c) {
    const int nc = n0 + c * 128;
    __syncthreads();  // previous chunk's reads done before restaging
#pragma unroll
    for (int i = 0; i < 4; ++i) {
      const int cid = i * 256 + tid;
      const int tok = cid & 127, db = cid >> 7;
      const int n = nc + tok;
      const size_t base = (size_t)(b * kN + n) * kQKVN + h * kD + db * 8;
      bf16x8 kv = *(const bf16x8*)(qkv + base + kC);  // K slice
      bf16x8 fv = *(const bf16x8*)(freqs + (size_t)n * kD + db * 8);
      *(bf16x8*)&k8[(db * 128 + tok) * 8] = rope8(kv, fv);
      bf16x8 vv = *(const bf16x8*)(qkv + base + 2 * kC);  // V slice
      const int tb = tok >> 3, sl = tok & 7;
#pragma unroll
      for (int e = 0; e < 8; ++e) {
        const int d = db * 8 + e;
        ((bf16*)v8)[((tb * 64) + (d ^ (tb & 7))) * 8 + sl] = vv[e];
      }
    }
    __syncthreads();

#pragma unroll
    for (int g = 0; g < 4; ++g) {
      // S^T = K Q^T over d=64: lane holds toks {j*16 + q4*4 + r} for q = g*16+l16
      f32x4 S[8] = {};
#pragma unroll
      for (int j = 0; j < 8; ++j)
#pragma unroll
        for (int s = 0; s < 2; ++s) {
          bf16x8 kf = *(const bf16x8*)&k8[((q4 + 4 * s) * 128 + j * 16 + l16) * 8];
          S[j] = MFMA(kf, qf[g][s], S[j]);  // swapped operands
        }
      // scale + in-lane max over 32 tokens (4 parallel chains), then cross-q4
      float m0_ = -3.0e38f, m1_ = -3.0e38f, m2_ = -3.0e38f, m3_ = -3.0e38f;
#pragma unroll
      for (int j = 0; j < 8; ++j) {
        S[j][0] *= scale; S[j][1] *= scale; S[j][2] *= scale; S[j][3] *= scale;
        m0_ = fmaxf(m0_, S[j][0]); m1_ = fmaxf(m1_, S[j][1]);
        m2_ = fmaxf(m2_, S[j][2]); m3_ = fmaxf(m3_, S[j][3]);
      }
      float mx = fmaxf(fmaxf(m0_, m1_), fmaxf(m2_, m3_));
      mx = fmaxf(mx, __shfl_xor(mx, 16));
      mx = fmaxf(mx, __shfl_xor(mx, 32));
      const float mnew = fmaxf(mrow[g], mx);
      const float al = __expf(mrow[g] - mnew);
      mrow[g] = mnew;
      float s0 = 0.f, s1 = 0.f, s2 = 0.f, s3 = 0.f;
#pragma unroll
      for (int j = 0; j < 8; ++j) {
        S[j][0] = __expf(S[j][0] - mnew); s0 += S[j][0];
        S[j][1] = __expf(S[j][1] - mnew); s1 += S[j][1];
        S[j][2] = __expf(S[j][2] - mnew); s2 += S[j][2];
        S[j][3] = __expf(S[j][3] - mnew); s3 += S[j][3];
      }
      float sm = (s0 + s1) + (s2 + s3);
      sm += __shfl_xor(sm, 16);
      sm += __shfl_xor(sm, 32);
      lrow[g] = lrow[g] * al + sm;
      // redistribute alpha to O-row owners (O rows are q = q4*4+r; al lives at lane l16=q)
      float alr[4];
#pragma unroll
      for (int r = 0; r < 4; ++r) alr[r] = __shfl(al, q4 * 4 + r);
#pragma unroll
      for (int jd = 0; jd < 4; ++jd)
#pragma unroll
        for (int r = 0; r < 4; ++r) O[g][jd][r] *= alr[r];
      // P writes: 8 x b64, layout pT[q=l16][tok], swizzled; lane's 4 r = 4 consecutive toks
#pragma unroll
      for (int j = 0; j < 8; ++j) {
        bf16x4 pk = {(bf16)S[j][0], (bf16)S[j][1], (bf16)S[j][2], (bf16)S[j][3]};
        *(bf16x4*)(pw + l16 * 256 + ((j * 32 + q4 * 8) ^ swz)) = pk;
      }
      asm volatile("s_waitcnt lgkmcnt(0)" ::: "memory");  // P writes visible (same wave)
      // O += P V: pf = A-frag [row=q=l16][k=tok=s4*32+q4*8+e] via swizzled b128
#pragma unroll
      for (int s4 = 0; s4 < 4; ++s4) {
        bf16x8 pf = *(const bf16x8*)(pw + l16 * 256 + ((s4 * 64 + q4 * 16) ^ swz));
        const int tb2 = q4 + 4 * s4;
#pragma unroll
        for (int jd = 0; jd < 4; ++jd) {
          const int d2 = (l16 + 16 * jd) ^ (tb2 & 7);
          bf16x8 vf = *(const bf16x8*)&v8[(tb2 * 64 + d2) * 8];
          O[g][jd] = MFMA(pf, vf, O[g][jd]);
        }
      }
      asm volatile("" ::: "memory");  // keep next g's pT writes after this g's reads
    }
  }

  // epilogue: normalize (lrow lives at lane l16=q; O rows are q=q4*4+r), write bf16
#pragma unroll
  for (int g = 0; g < 4; ++g) {
    float lr[4];
#pragma unroll
    for (int r = 0; r < 4; ++r) lr[r] = __shfl(lrow[g], q4 * 4 + r);
    const int nb = n0 + wave * 64 + g * 16 + q4 * 4;
#pragma unroll
    for (int jd = 0; jd < 4; ++jd) {
      const int d = l16 + 16 * jd;
#pragma unroll
      for (int r = 0; r < 4; ++r) {
        const float v = O[g][jd][r] / lr[r];
        ob[(size_t)(b * kN + nb + r) * kC + h * kD + d] = (bf16)v;
      }
    }
  }
}

extern "C" void kernel_launch(void* const* d_in, const int* in_sizes, int n_in,
                              void* d_out, int out_size, void* d_ws, size_t ws_size,
                              hipStream_t stream) {
  (void)in_sizes; (void)n_in; (void)out_size; (void)ws_size;
  const float* x      = (const float*)d_in[0];
  const float* freqs  = (const float*)d_in[1];
  const float* qkv_w  = (const float*)d_in[2];
  const float* proj_w = (const float*)d_in[3];
  const float* proj_b = (const float*)d_in[4];
  float* out = (float*)d_out;

  // workspace layout (bf16 elems):
  //  [qkv_buf: kM*kQKVN][shared: kM*kC (x_bf16 then attn_buf)][qkvw][projw][freqs]
  bf16* qkv_buf = (bf16*)d_ws;
  bf16* shared  = qkv_buf + (size_t)kM * kQKVN;
  bf16* x_b     = shared;                     // live: convert -> gemm1
  bf16* attn_b  = shared;                     // live: attn -> gemm2
  bf16* qkvw_b  = shared + (size_t)kM * kC;
  bf16* projw_b = qkvw_b + (size_t)kQKVN * kC;
  bf16* freqs_b = projw_b + (size_t)kC * kC;

  // fp32 -> bf16 conversions
  cvt_bf16<<<(kM * kC / 4 + 255) / 256, 256, 0, stream>>>(x, x_b, kM * kC / 4);
  cvt_bf16<<<(kQKVN * kC / 4 + 255) / 256, 256, 0, stream>>>(qkv_w, qkvw_b, kQKVN * kC / 4);
  cvt_bf16<<<(kC * kC / 4 + 255) / 256, 256, 0, stream>>>(proj_w, projw_b, kC * kC / 4);
  cvt_bf16<<<(kN * kD / 4 + 255) / 256, 256, 0, stream>>>(freqs, freqs_b, kN * kD / 4);

  gemm_bt<kQKVN, false, bf16><<<dim3(kQKVN / 256, kM / 256), 512, 0, stream>>>(
      x_b, qkvw_b, nullptr, qkv_buf);
  attn_win<<<dim3(kB * kH * (kN / 256)), 256, 0, stream>>>(qkv_buf, freqs_b, attn_b);
  gemm_bt<kC, true, float><<<dim3(kC / 256, kM / 256), 512, 0, stream>>>(
      attn_b, projw_b, proj_b, out);
}

// Round 7
// 375.745 us; speedup vs baseline: 3.9735x; 3.9735x over previous
//
#include <hip/hip_runtime.h>
#include <stdint.h>
#include <stddef.h>

typedef __bf16 bf16;
typedef __bf16 bf16x4 __attribute__((ext_vector_type(4)));
typedef __bf16 bf16x8 __attribute__((ext_vector_type(8)));
typedef float f32x4 __attribute__((ext_vector_type(4)));

#define MFMA(a, b, c) __builtin_amdgcn_mfma_f32_16x16x32_bf16(a, b, c, 0, 0, 0)

static constexpr int kB = 4, kN = 4096, kC = 1024, kH = 16, kD = 64;
static constexpr int kM = kB * kN;   // 16384 token rows
static constexpr int kK = 1024;      // contraction dim for both GEMMs
static constexpr int kQKVN = 3072;

// async 16B global->LDS (direct-to-LDS DMA; dest = wave-uniform base + lane*16)
__device__ __forceinline__ void cp16(const void* g, void* l) {
  __builtin_amdgcn_global_load_lds(
      (const __attribute__((address_space(1))) void*)g,
      (__attribute__((address_space(3))) void*)l, 16, 0, 0);
}

// fp32 -> bf16 elementwise convert, 4 elems/thread
__global__ __launch_bounds__(256) void cvt_bf16(const float* __restrict__ src,
                                                bf16* __restrict__ dst, int n4) {
  const int i = blockIdx.x * 256 + threadIdx.x;
  if (i < n4) {
    const float4 v = ((const float4*)src)[i];
    bf16x4 o = {(bf16)v.x, (bf16)v.y, (bf16)v.z, (bf16)v.w};
    *(bf16x4*)&dst[4 * i] = o;
  }
}

// rope on 8 consecutive d-elements (4 aligned pairs)
__device__ __forceinline__ bf16x8 rope8(bf16x8 t, bf16x8 f) {
  bf16x8 o;
#pragma unroll
  for (int p = 0; p < 4; ++p) {
    float t0 = (float)t[2 * p], t1 = (float)t[2 * p + 1];
    float f0 = (float)f[2 * p], f1 = (float)f[2 * p + 1];
    o[2 * p]     = (bf16)(t0 * f0 - t1 * f1);
    o[2 * p + 1] = (bf16)(t1 * f0 + t0 * f1);
  }
  return o;
}

// C[m][n] = sum_k A[m][k] * Bw[n][k] (+ bias[n]).  A: kM x kK, Bw: NOUT x kK (bf16 row-major).
//
// m201-style 4-PHASE-PER-K-TILE schedule (T2+T3+T4+T5), BK=64, ring-2, 1 block/CU:
//   256x256 tile, 8 waves (2M x 4N, each 128x64 out), LDS = 2 bufs x (A 32KB + B 32KB)
//   = 128 KB. K-tile t (K=64, 2 mfma k-steps), 4 phases, each:
//     { ds_read quadrant frags ; stage ONE half-tile (2 cp16) ; s_barrier ;
//       setprio(1) 16 MFMA setprio(0) ; s_barrier }
//   ph0: read a[0-3][ks01] + b[0-1][ks01] (12 b128); stage A(t+1) half0; MFMA i0-3 x j0-1
//   ph1: read b[2-3][ks01] (4);                 stage A(t+1) half1; MFMA i0-3 x j2-3
//   ph2: read a[4-7][ks01] (8);                 stage B(t+2) half0; MFMA i4-7 x j0-1
//   ph3: no reads; stage B(t+2) half1; s_waitcnt vmcnt(4);          MFMA i4-7 x j2-3
//   Ledger (verified): A(t+1) staged t:ph0/1, confirmed at t:ph3's vmcnt(4) (the 2
//   unconfirmed halves are B(t+2) from ph2/3), published by ph3 barrier, first read
//   t+1:ph0/ph2. B(t+1) staged t-1:ph2/3 (5-6 stages old at t:ph3) -> confirmed.
//   WAR: each phase's LDS reads are consumed by that phase's MFMA (compiler lgkm)
//   BEFORE its trailing barrier, so a stage issued after that barrier cannot land on
//   live data. A(t+1) writes buf[(t+1)&1].A (last read t-1:ph2); B(t+2) writes
//   buf[t&1].B (last read t:ph1, stage issues t:ph2/3). Tail: vmcnt(0) when t+2>=NT.
//   LDS per half: [row 128][kbslot 8][8 elems]; stored slot (ks*4+s) holds global
//   k-chunk ks*4 + (s ^ ((row>>1)&3)): cp16 coalesced (8 lanes = one row = 128B,
//   2 full lines) and conflict-free swizzled b128 reads (XOR term lane-constant).
template <int NOUT, bool BIAS, typename OutT>
__global__ __launch_bounds__(512, 2) void gemm_bt(const bf16* __restrict__ A,
                                                  const bf16* __restrict__ Bw,
                                                  const float* __restrict__ bias,
                                                  OutT* __restrict__ Cout) {
  __shared__ unsigned short As[2][2][8192];  // [buf][half][row*64 + kbslot*8 + e]
  __shared__ unsigned short Bs[2][2][8192];
  const int tid = threadIdx.x;
  const int wave = tid >> 6, lane = tid & 63;
  const int q4 = lane >> 4, l16 = lane & 15;
  const int wr = wave >> 2, wc = wave & 3;

  const int nwg = gridDim.x * gridDim.y;
  int bid = blockIdx.y * gridDim.x + blockIdx.x;
  bid = (bid & 7) * (nwg >> 3) + (bid >> 3);
  const int bx = bid % gridDim.x, by = bid / gridDim.x;
  const int n0 = bx * 256, m0 = by * 256;

  constexpr int NT = kK / 64;  // 16 K-tiles of K=64

  f32x4 acc[8][4] = {};

  auto stageA = [&](int kt, int half) {
    const int buf = kt & 1;
#pragma unroll
    for (int i = 0; i < 2; ++i) {
      const int c = i * 512 + tid;               // 0..1023 chunks of 16B
      const int row = c >> 3, slot = c & 7;      // 8 lanes cover one row (128B)
      const int ks = slot >> 2, s = slot & 3;
      const int kb = ks * 4 + (s ^ ((row >> 1) & 3));
      cp16(A + (size_t)(m0 + half * 128 + row) * kK + kt * 64 + kb * 8,
           &As[buf][half][c * 8]);
    }
  };
  auto stageB = [&](int kt, int half) {
    const int buf = kt & 1;
#pragma unroll
    for (int i = 0; i < 2; ++i) {
      const int c = i * 512 + tid;
      const int row = c >> 3, slot = c & 7;
      const int ks = slot >> 2, s = slot & 3;
      const int kb = ks * 4 + (s ^ ((row >> 1) & 3));
      cp16(Bw + (size_t)(n0 + half * 128 + row) * kK + kt * 64 + kb * 8,
           &Bs[buf][half][c * 8]);
    }
  };

  // prologue: A(0),B(0),B(1); confirm A(0)+B(0) (leave B(1)'s 4 loads in flight)
  stageA(0, 0); stageA(0, 1); stageB(0, 0); stageB(0, 1); stageB(1, 0); stageB(1, 1);
  asm volatile("s_waitcnt vmcnt(4)\n\ts_barrier" ::: "memory");

  const int slot8 = (q4 ^ ((l16 >> 1) & 3)) * 8;  // lane-constant read swizzle
  const int brow = (wc & 1) * 64;                 // row base within B half

  for (int t = 0; t < NT; ++t) {
    const int rb = t & 1;
    const unsigned short* Ab = &As[rb][wr][0];
    const unsigned short* Bb = &Bs[rb][wc >> 1][0];
    bf16x8 a[4][2], b[4][2];

    // ---- phase 0: a[0-3] + b[0-1]; stage A(t+1) half0; MFMA quadrant (i0-3, j0-1)
#pragma unroll
    for (int i = 0; i < 4; ++i) {
      const int row = i * 16 + l16;
      a[i][0] = *(const bf16x8*)&Ab[row * 64 + slot8];
      a[i][1] = *(const bf16x8*)&Ab[row * 64 + 32 + slot8];
    }
#pragma unroll
    for (int j = 0; j < 2; ++j) {
      const int row = brow + j * 16 + l16;
      b[j][0] = *(const bf16x8*)&Bb[row * 64 + slot8];
      b[j][1] = *(const bf16x8*)&Bb[row * 64 + 32 + slot8];
    }
    if (t + 1 < NT) stageA(t + 1, 0);
    asm volatile("s_barrier" ::: "memory");
    __builtin_amdgcn_s_setprio(1);
#pragma unroll
    for (int i = 0; i < 4; ++i)
#pragma unroll
      for (int j = 0; j < 2; ++j)
#pragma unroll
        for (int ks = 0; ks < 2; ++ks)
          acc[i][j] = MFMA(a[i][ks], b[j][ks], acc[i][j]);
    __builtin_amdgcn_s_setprio(0);
    asm volatile("s_barrier" ::: "memory");

    // ---- phase 1: b[2-3]; stage A(t+1) half1; MFMA (i0-3, j2-3)
#pragma unroll
    for (int j = 2; j < 4; ++j) {
      const int row = brow + j * 16 + l16;
      b[j][0] = *(const bf16x8*)&Bb[row * 64 + slot8];
      b[j][1] = *(const bf16x8*)&Bb[row * 64 + 32 + slot8];
    }
    if (t + 1 < NT) stageA(t + 1, 1);
    asm volatile("s_barrier" ::: "memory");
    __builtin_amdgcn_s_setprio(1);
#pragma unroll
    for (int i = 0; i < 4; ++i)
#pragma unroll
      for (int j = 2; j < 4; ++j)
#pragma unroll
        for (int ks = 0; ks < 2; ++ks)
          acc[i][j] = MFMA(a[i][ks], b[j][ks], acc[i][j]);
    __builtin_amdgcn_s_setprio(0);
    asm volatile("s_barrier" ::: "memory");

    // ---- phase 2: a[4-7] (reuse regs); stage B(t+2) half0; MFMA (i4-7, j0-1)
#pragma unroll
    for (int i = 0; i < 4; ++i) {
      const int row = (4 + i) * 16 + l16;
      a[i][0] = *(const bf16x8*)&Ab[row * 64 + slot8];
      a[i][1] = *(const bf16x8*)&Ab[row * 64 + 32 + slot8];
    }
    if (t + 2 < NT) stageB(t + 2, 0);
    asm volatile("s_barrier" ::: "memory");
    __builtin_amdgcn_s_setprio(1);
#pragma unroll
    for (int i = 0; i < 4; ++i)
#pragma unroll
      for (int j = 0; j < 2; ++j)
#pragma unroll
        for (int ks = 0; ks < 2; ++ks)
          acc[4 + i][j] = MFMA(a[i][ks], b[j][ks], acc[4 + i][j]);
    __builtin_amdgcn_s_setprio(0);
    asm volatile("s_barrier" ::: "memory");

    // ---- phase 3: no reads; stage B(t+2) half1; counted wait; MFMA (i4-7, j2-3)
    if (t + 2 < NT) {
      stageB(t + 2, 1);
      asm volatile("s_waitcnt vmcnt(4)\n\ts_barrier" ::: "memory");
    } else {
      asm volatile("s_waitcnt vmcnt(0)\n\ts_barrier" ::: "memory");
    }
    __builtin_amdgcn_s_setprio(1);
#pragma unroll
    for (int i = 0; i < 4; ++i)
#pragma unroll
      for (int j = 2; j < 4; ++j)
#pragma unroll
        for (int ks = 0; ks < 2; ++ks)
          acc[4 + i][j] = MFMA(a[i][ks], b[j][ks], acc[4 + i][j]);
    __builtin_amdgcn_s_setprio(0);
    asm volatile("s_barrier" ::: "memory");
  }

  // epilogue: C/D layout col=lane&15, row=(lane>>4)*4+reg
#pragma unroll
  for (int i = 0; i < 8; ++i) {
    const int rowb = m0 + wr * 128 + i * 16 + q4 * 4;
#pragma unroll
    for (int j = 0; j < 4; ++j) {
      const int col = n0 + wc * 64 + j * 16 + l16;
      const float bv = BIAS ? bias[col] : 0.0f;
#pragma unroll
      for (int r = 0; r < 4; ++r)
        Cout[(size_t)(rowb + r) * NOUT + col] = (OutT)(acc[i][j][r] + bv);
    }
  }
}

// One block per (b,h,w) window. 4 waves x 64 q-rows, q-groups of 16 rows.
// SWAPPED-OPERAND flash attention: S^T = mfma(K, Q) so each lane owns the
// token axis (softmax axis) for one query column q=l16:
//  - softmax: 31 in-lane ops + 2 shfl_xor (vs 32 bpermutes)
//  - P round-trip: lane's 4 values = 4 consecutive tokens -> packed b64 writes
//    into pT[q][tok] (XOR-swizzled, conflict-free), b128 reads as PV A-frag
//  - V transpose staging XOR-swizzled: 16-way write conflict -> conflict-free
__global__ __launch_bounds__(256) void attn_win(const bf16* __restrict__ qkv,
                                                const bf16* __restrict__ freqs,
                                                bf16* __restrict__ ob) {
  __shared__ unsigned short k8[8 * 128 * 8];  // [dblk][tok][8]  16 KB (roped K)
  __shared__ unsigned short v8[16 * 64 * 8];  // [tokblk][d^swz][8] 16 KB (V^T)
  __shared__ unsigned short pT[4][16 * 128];  // per wave [q:16][tok:128] 4 KB

  const int bid = blockIdx.x;
  const int w = bid & 15, h = (bid >> 4) & 15, b = bid >> 8;
  const int n0 = w * 256;
  const int tid = threadIdx.x;
  const int wave = tid >> 6, lane = tid & 63;
  const int q4 = lane >> 4, l16 = lane & 15;
  const float scale = 0.125f;  // D^-0.5
  const int swz = (l16 & 7) << 4;  // byte XOR for pT (bits 4-6)
  char* const pw = (char*)&pT[wave][0];

  // q fragments with rope, hoisted (B-frag: col=l16=q, k=(q4)*8+e, s picks d-half)
  bf16x8 qf[4][2];
#pragma unroll
  for (int g = 0; g < 4; ++g) {
    const int n = n0 + wave * 64 + g * 16 + l16;
    const bf16* qrow = qkv + (size_t)(b * kN + n) * kQKVN + h * kD;
    const bf16* frow = freqs + (size_t)n * kD;
#pragma unroll
    for (int s = 0; s < 2; ++s) {
      const int d0 = s * 32 + q4 * 8;
      qf[g][s] = rope8(*(const bf16x8*)(qrow + d0), *(const bf16x8*)(frow + d0));
    }
  }

  f32x4 O[4][4] = {};       // [group][d-tile]; rows q=q4*4+r, cols d=l16+16*jd
  float mrow[4], lrow[4];   // per-lane stats for q = g*16 + l16
#pragma unroll
  for (int g = 0; g < 4; ++g) { mrow[g] = -3.0e38f; lrow[g] = 0.0f; }

  for (int c = 0; c < 2; ++c) {
    const int nc = n0 + c * 128;
    __syncthreads();  // previous chunk's reads done before restaging
#pragma unroll
    for (int i = 0; i < 4; ++i) {
      const int cid = i * 256 + tid;
      const int tok = cid & 127, db = cid >> 7;
      const int n = nc + tok;
      const size_t base = (size_t)(b * kN + n) * kQKVN + h * kD + db * 8;
      bf16x8 kv = *(const bf16x8*)(qkv + base + kC);  // K slice
      bf16x8 fv = *(const bf16x8*)(freqs + (size_t)n * kD + db * 8);
      *(bf16x8*)&k8[(db * 128 + tok) * 8] = rope8(kv, fv);
      bf16x8 vv = *(const bf16x8*)(qkv + base + 2 * kC);  // V slice
      const int tb = tok >> 3, sl = tok & 7;
#pragma unroll
      for (int e = 0; e < 8; ++e) {
        const int d = db * 8 + e;
        ((bf16*)v8)[((tb * 64) + (d ^ (tb & 7))) * 8 + sl] = vv[e];
      }
    }
    __syncthreads();

#pragma unroll
    for (int g = 0; g < 4; ++g) {
      // S^T = K Q^T over d=64: lane holds toks {j*16 + q4*4 + r} for q = g*16+l16
      f32x4 S[8] = {};
#pragma unroll
      for (int j = 0; j < 8; ++j)
#pragma unroll
        for (int s = 0; s < 2; ++s) {
          bf16x8 kf = *(const bf16x8*)&k8[((q4 + 4 * s) * 128 + j * 16 + l16) * 8];
          S[j] = MFMA(kf, qf[g][s], S[j]);  // swapped operands
        }
      // scale + in-lane max over 32 tokens (4 parallel chains), then cross-q4
      float m0_ = -3.0e38f, m1_ = -3.0e38f, m2_ = -3.0e38f, m3_ = -3.0e38f;
#pragma unroll
      for (int j = 0; j < 8; ++j) {
        S[j][0] *= scale; S[j][1] *= scale; S[j][2] *= scale; S[j][3] *= scale;
        m0_ = fmaxf(m0_, S[j][0]); m1_ = fmaxf(m1_, S[j][1]);
        m2_ = fmaxf(m2_, S[j][2]); m3_ = fmaxf(m3_, S[j][3]);
      }
      float mx = fmaxf(fmaxf(m0_, m1_), fmaxf(m2_, m3_));
      mx = fmaxf(mx, __shfl_xor(mx, 16));
      mx = fmaxf(mx, __shfl_xor(mx, 32));
      const float mnew = fmaxf(mrow[g], mx);
      const float al = __expf(mrow[g] - mnew);
      mrow[g] = mnew;
      float s0 = 0.f, s1 = 0.f, s2 = 0.f, s3 = 0.f;
#pragma unroll
      for (int j = 0; j < 8; ++j) {
        S[j][0] = __expf(S[j][0] - mnew); s0 += S[j][0];
        S[j][1] = __expf(S[j][1] - mnew); s1 += S[j][1];
        S[j][2] = __expf(S[j][2] - mnew); s2 += S[j][2];
        S[j][3] = __expf(S[j][3] - mnew); s3 += S[j][3];
      }
      float sm = (s0 + s1) + (s2 + s3);
      sm += __shfl_xor(sm, 16);
      sm += __shfl_xor(sm, 32);
      lrow[g] = lrow[g] * al + sm;
      // redistribute alpha to O-row owners (O rows are q = q4*4+r; al lives at lane l16=q)
      float alr[4];
#pragma unroll
      for (int r = 0; r < 4; ++r) alr[r] = __shfl(al, q4 * 4 + r);
#pragma unroll
      for (int jd = 0; jd < 4; ++jd)
#pragma unroll
        for (int r = 0; r < 4; ++r) O[g][jd][r] *= alr[r];
      // P writes: 8 x b64, layout pT[q=l16][tok], swizzled; lane's 4 r = 4 consecutive toks
#pragma unroll
      for (int j = 0; j < 8; ++j) {
        bf16x4 pk = {(bf16)S[j][0], (bf16)S[j][1], (bf16)S[j][2], (bf16)S[j][3]};
        *(bf16x4*)(pw + l16 * 256 + ((j * 32 + q4 * 8) ^ swz)) = pk;
      }
      asm volatile("s_waitcnt lgkmcnt(0)" ::: "memory");  // P writes visible (same wave)
      // O += P V: pf = A-frag [row=q=l16][k=tok=s4*32+q4*8+e] via swizzled b128
#pragma unroll
      for (int s4 = 0; s4 < 4; ++s4) {
        bf16x8 pf = *(const bf16x8*)(pw + l16 * 256 + ((s4 * 64 + q4 * 16) ^ swz));
        const int tb2 = q4 + 4 * s4;
#pragma unroll
        for (int jd = 0; jd < 4; ++jd) {
          const int d2 = (l16 + 16 * jd) ^ (tb2 & 7);
          bf16x8 vf = *(const bf16x8*)&v8[(tb2 * 64 + d2) * 8];
          O[g][jd] = MFMA(pf, vf, O[g][jd]);
        }
      }
      asm volatile("" ::: "memory");  // keep next g's pT writes after this g's reads
    }
  }

  // epilogue: normalize (lrow lives at lane l16=q; O rows are q=q4*4+r), write bf16
#pragma unroll
  for (int g = 0; g < 4; ++g) {
    float lr[4];
#pragma unroll
    for (int r = 0; r < 4; ++r) lr[r] = __shfl(lrow[g], q4 * 4 + r);
    const int nb = n0 + wave * 64 + g * 16 + q4 * 4;
#pragma unroll
    for (int jd = 0; jd < 4; ++jd) {
      const int d = l16 + 16 * jd;
#pragma unroll
      for (int r = 0; r < 4; ++r) {
        const float v = O[g][jd][r] / lr[r];
        ob[(size_t)(b * kN + nb + r) * kC + h * kD + d] = (bf16)v;
      }
    }
  }
}

extern "C" void kernel_launch(void* const* d_in, const int* in_sizes, int n_in,
                              void* d_out, int out_size, void* d_ws, size_t ws_size,
                              hipStream_t stream) {
  (void)in_sizes; (void)n_in; (void)out_size; (void)ws_size;
  const float* x      = (const float*)d_in[0];
  const float* freqs  = (const float*)d_in[1];
  const float* qkv_w  = (const float*)d_in[2];
  const float* proj_w = (const float*)d_in[3];
  const float* proj_b = (const float*)d_in[4];
  float* out = (float*)d_out;

  // workspace layout (bf16 elems):
  //  [qkv_buf: kM*kQKVN][shared: kM*kC (x_bf16 then attn_buf)][qkvw][projw][freqs]
  bf16* qkv_buf = (bf16*)d_ws;
  bf16* shared  = qkv_buf + (size_t)kM * kQKVN;
  bf16* x_b     = shared;                     // live: convert -> gemm1
  bf16* attn_b  = shared;                     // live: attn -> gemm2
  bf16* qkvw_b  = shared + (size_t)kM * kC;
  bf16* projw_b = qkvw_b + (size_t)kQKVN * kC;
  bf16* freqs_b = projw_b + (size_t)kC * kC;

  // fp32 -> bf16 conversions
  cvt_bf16<<<(kM * kC / 4 + 255) / 256, 256, 0, stream>>>(x, x_b, kM * kC / 4);
  cvt_bf16<<<(kQKVN * kC / 4 + 255) / 256, 256, 0, stream>>>(qkv_w, qkvw_b, kQKVN * kC / 4);
  cvt_bf16<<<(kC * kC / 4 + 255) / 256, 256, 0, stream>>>(proj_w, projw_b, kC * kC / 4);
  cvt_bf16<<<(kN * kD / 4 + 255) / 256, 256, 0, stream>>>(freqs, freqs_b, kN * kD / 4);

  gemm_bt<kQKVN, false, bf16><<<dim3(kQKVN / 256, kM / 256), 512, 0, stream>>>(
      x_b, qkvw_b, nullptr, qkv_buf);
  attn_win<<<dim3(kB * kH * (kN / 256)), 256, 0, stream>>>(qkv_buf, freqs_b, attn_b);
  gemm_bt<kC, true, float><<<dim3(kC / 256, kM / 256), 512, 0, stream>>>(
      attn_b, projw_b, proj_b, out);
}

// Round 8
// 362.532 us; speedup vs baseline: 4.1183x; 1.0364x over previous
//
#include <hip/hip_runtime.h>
#include <stdint.h>
#include <stddef.h>

typedef __bf16 bf16;
typedef __bf16 bf16x4 __attribute__((ext_vector_type(4)));
typedef __bf16 bf16x8 __attribute__((ext_vector_type(8)));
typedef float f32x4 __attribute__((ext_vector_type(4)));

#define MFMA(a, b, c) __builtin_amdgcn_mfma_f32_16x16x32_bf16(a, b, c, 0, 0, 0)

static constexpr int kB = 4, kN = 4096, kC = 1024, kH = 16, kD = 64;
static constexpr int kM = kB * kN;   // 16384 token rows
static constexpr int kK = 1024;      // contraction dim for both GEMMs
static constexpr int kQKVN = 3072;

// async 16B global->LDS (direct-to-LDS DMA; dest = wave-uniform base + lane*16)
__device__ __forceinline__ void cp16(const void* g, void* l) {
  __builtin_amdgcn_global_load_lds(
      (const __attribute__((address_space(1))) void*)g,
      (__attribute__((address_space(3))) void*)l, 16, 0, 0);
}

// fp32 -> bf16 elementwise convert, 4 elems/thread
__global__ __launch_bounds__(256) void cvt_bf16(const float* __restrict__ src,
                                                bf16* __restrict__ dst, int n4) {
  const int i = blockIdx.x * 256 + threadIdx.x;
  if (i < n4) {
    const float4 v = ((const float4*)src)[i];
    bf16x4 o = {(bf16)v.x, (bf16)v.y, (bf16)v.z, (bf16)v.w};
    *(bf16x4*)&dst[4 * i] = o;
  }
}

// rope on 8 consecutive d-elements (4 aligned pairs)
__device__ __forceinline__ bf16x8 rope8(bf16x8 t, bf16x8 f) {
  bf16x8 o;
#pragma unroll
  for (int p = 0; p < 4; ++p) {
    float t0 = (float)t[2 * p], t1 = (float)t[2 * p + 1];
    float f0 = (float)f[2 * p], f1 = (float)f[2 * p + 1];
    o[2 * p]     = (bf16)(t0 * f0 - t1 * f1);
    o[2 * p + 1] = (bf16)(t1 * f0 + t0 * f1);
  }
  return o;
}

// C[m][n] = sum_k A[m][k] * Bw[n][k] (+ bias[n]).  A: kM x kK, Bw: NOUT x kK (bf16 row-major).
//
// m201-style 4-PHASE-PER-K-TILE schedule (T2+T3+T4+T5), BK=64, ring-2, 1 block/CU.
// ROUND-7 FIX: LDS half-tile layout is now k-step-PLANED [ks:2][row:128][slot:4][16B]
// (row stride 64 B, NOT 128 B). Round-6's [row][8 slots] layout had bank_start =
// 4*swz only (row*128B = 32 banks = 0 mod 32) -> all lanes in half the banks,
// 9.4M conflict-cycles. Planed layout restores the round-2 bank pattern
// (16*l16 + 4*(q4^((l16>>1)&3)); measured 0 conflicts).
//   Staging: chunk c in 0..1023, dest = c*16B linear (cp16-compatible);
//   c -> ks=c>>9, row=(c>>2)&127, s=c&3; global source chunk kb = ks*4 + (s ^
//   ((row>>1)&3)) (inverse-swizzle; 4 lanes cover one full 64B line per row).
//   Read: frag (i,ks) at (ks*128+row)*64B + (q4^((l16>>1)&3))*16B — retrieves
//   global k-chunk ks*4+q4 (XOR involution), lane-constant swizzle term.
// Schedule per K-tile t (4 phases, each {ds_read quadrant ; stage ONE half (2 cp16) ;
// barrier ; setprio(1) 16 MFMA setprio(0) ; barrier}):
//   ph0: read a[0-3][ks01]+b[0-1][ks01]; stage A(t+1) h0
//   ph1: read b[2-3][ks01];              stage A(t+1) h1
//   ph2: read a[4-7][ks01];              stage B(t+2) h0
//   ph3: no reads;                       stage B(t+2) h1 ; s_waitcnt vmcnt(4)
// Ledger: A(t+1) staged t:ph0/1, confirmed t:ph3 vmcnt(4) (2 unconfirmed halves =
// B(t+2)), published ph3 barrier, first read t+1:ph0. B(t+1) staged t-1:ph2/3,
// long confirmed. WAR: stage targets' last reads complete (lgkm before MFMA use)
// ahead of the trailing barrier each stage issues after. Tail: vmcnt(0) at t+2>=NT.
template <int NOUT, bool BIAS, typename OutT>
__global__ __launch_bounds__(512, 2) void gemm_bt(const bf16* __restrict__ A,
                                                  const bf16* __restrict__ Bw,
                                                  const float* __restrict__ bias,
                                                  OutT* __restrict__ Cout) {
  __shared__ unsigned short As[2][2][8192];  // [buf][half][(ks*128+row)*32 + slot*8 + e]
  __shared__ unsigned short Bs[2][2][8192];
  const int tid = threadIdx.x;
  const int wave = tid >> 6, lane = tid & 63;
  const int q4 = lane >> 4, l16 = lane & 15;
  const int wr = wave >> 2, wc = wave & 3;

  const int nwg = gridDim.x * gridDim.y;
  int bid = blockIdx.y * gridDim.x + blockIdx.x;
  bid = (bid & 7) * (nwg >> 3) + (bid >> 3);
  const int bx = bid % gridDim.x, by = bid / gridDim.x;
  const int n0 = bx * 256, m0 = by * 256;

  constexpr int NT = kK / 64;  // 16 K-tiles of K=64

  f32x4 acc[8][4] = {};

  auto stageA = [&](int kt, int half) {
    const int buf = kt & 1;
#pragma unroll
    for (int i = 0; i < 2; ++i) {
      const int c = i * 512 + tid;  // 0..1023; LDS dest = c*16B (linear)
      const int ks = c >> 9, row = (c >> 2) & 127, s = c & 3;
      const int kb = ks * 4 + (s ^ ((row >> 1) & 3));
      cp16(A + (size_t)(m0 + half * 128 + row) * kK + kt * 64 + kb * 8,
           &As[buf][half][c * 8]);
    }
  };
  auto stageB = [&](int kt, int half) {
    const int buf = kt & 1;
#pragma unroll
    for (int i = 0; i < 2; ++i) {
      const int c = i * 512 + tid;
      const int ks = c >> 9, row = (c >> 2) & 127, s = c & 3;
      const int kb = ks * 4 + (s ^ ((row >> 1) & 3));
      cp16(Bw + (size_t)(n0 + half * 128 + row) * kK + kt * 64 + kb * 8,
           &Bs[buf][half][c * 8]);
    }
  };

  // prologue: A(0),B(0),B(1); confirm A(0)+B(0) (leave B(1)'s 4 loads in flight)
  stageA(0, 0); stageA(0, 1); stageB(0, 0); stageB(0, 1); stageB(1, 0); stageB(1, 1);
  asm volatile("s_waitcnt vmcnt(4)\n\ts_barrier" ::: "memory");

  const int s8 = (q4 ^ ((l16 >> 1) & 3)) * 8;  // lane-constant read swizzle (shorts)
  const int brow = (wc & 1) * 64;              // row base within B half

  for (int t = 0; t < NT; ++t) {
    const int rb = t & 1;
    const unsigned short* Ab = &As[rb][wr][0];
    const unsigned short* Bb = &Bs[rb][wc >> 1][0];
    bf16x8 a[4][2], b[4][2];

    // ---- phase 0: a[0-3] + b[0-1]; stage A(t+1) half0; MFMA (i0-3, j0-1)
#pragma unroll
    for (int i = 0; i < 4; ++i) {
      const int row = i * 16 + l16;
      a[i][0] = *(const bf16x8*)&Ab[row * 32 + s8];
      a[i][1] = *(const bf16x8*)&Ab[(128 + row) * 32 + s8];
    }
#pragma unroll
    for (int j = 0; j < 2; ++j) {
      const int row = brow + j * 16 + l16;
      b[j][0] = *(const bf16x8*)&Bb[row * 32 + s8];
      b[j][1] = *(const bf16x8*)&Bb[(128 + row) * 32 + s8];
    }
    if (t + 1 < NT) stageA(t + 1, 0);
    asm volatile("s_barrier" ::: "memory");
    __builtin_amdgcn_s_setprio(1);
#pragma unroll
    for (int i = 0; i < 4; ++i)
#pragma unroll
      for (int j = 0; j < 2; ++j)
#pragma unroll
        for (int ks = 0; ks < 2; ++ks)
          acc[i][j] = MFMA(a[i][ks], b[j][ks], acc[i][j]);
    __builtin_amdgcn_s_setprio(0);
    asm volatile("s_barrier" ::: "memory");

    // ---- phase 1: b[2-3]; stage A(t+1) half1; MFMA (i0-3, j2-3)
#pragma unroll
    for (int j = 2; j < 4; ++j) {
      const int row = brow + j * 16 + l16;
      b[j][0] = *(const bf16x8*)&Bb[row * 32 + s8];
      b[j][1] = *(const bf16x8*)&Bb[(128 + row) * 32 + s8];
    }
    if (t + 1 < NT) stageA(t + 1, 1);
    asm volatile("s_barrier" ::: "memory");
    __builtin_amdgcn_s_setprio(1);
#pragma unroll
    for (int i = 0; i < 4; ++i)
#pragma unroll
      for (int j = 2; j < 4; ++j)
#pragma unroll
        for (int ks = 0; ks < 2; ++ks)
          acc[i][j] = MFMA(a[i][ks], b[j][ks], acc[i][j]);
    __builtin_amdgcn_s_setprio(0);
    asm volatile("s_barrier" ::: "memory");

    // ---- phase 2: a[4-7] (reuse regs); stage B(t+2) half0; MFMA (i4-7, j0-1)
#pragma unroll
    for (int i = 0; i < 4; ++i) {
      const int row = (4 + i) * 16 + l16;
      a[i][0] = *(const bf16x8*)&Ab[row * 32 + s8];
      a[i][1] = *(const bf16x8*)&Ab[(128 + row) * 32 + s8];
    }
    if (t + 2 < NT) stageB(t + 2, 0);
    asm volatile("s_barrier" ::: "memory");
    __builtin_amdgcn_s_setprio(1);
#pragma unroll
    for (int i = 0; i < 4; ++i)
#pragma unroll
      for (int j = 0; j < 2; ++j)
#pragma unroll
        for (int ks = 0; ks < 2; ++ks)
          acc[4 + i][j] = MFMA(a[i][ks], b[j][ks], acc[4 + i][j]);
    __builtin_amdgcn_s_setprio(0);
    asm volatile("s_barrier" ::: "memory");

    // ---- phase 3: no reads; stage B(t+2) half1; counted wait; MFMA (i4-7, j2-3)
    if (t + 2 < NT) {
      stageB(t + 2, 1);
      asm volatile("s_waitcnt vmcnt(4)\n\ts_barrier" ::: "memory");
    } else {
      asm volatile("s_waitcnt vmcnt(0)\n\ts_barrier" ::: "memory");
    }
    __builtin_amdgcn_s_setprio(1);
#pragma unroll
    for (int i = 0; i < 4; ++i)
#pragma unroll
      for (int j = 2; j < 4; ++j)
#pragma unroll
        for (int ks = 0; ks < 2; ++ks)
          acc[4 + i][j] = MFMA(a[i][ks], b[j][ks], acc[4 + i][j]);
    __builtin_amdgcn_s_setprio(0);
    asm volatile("s_barrier" ::: "memory");
  }

  // epilogue: C/D layout col=lane&15, row=(lane>>4)*4+reg
#pragma unroll
  for (int i = 0; i < 8; ++i) {
    const int rowb = m0 + wr * 128 + i * 16 + q4 * 4;
#pragma unroll
    for (int j = 0; j < 4; ++j) {
      const int col = n0 + wc * 64 + j * 16 + l16;
      const float bv = BIAS ? bias[col] : 0.0f;
#pragma unroll
      for (int r = 0; r < 4; ++r)
        Cout[(size_t)(rowb + r) * NOUT + col] = (OutT)(acc[i][j][r] + bv);
    }
  }
}

// One block per (b,h,w) window. 4 waves x 64 q-rows, q-groups of 16 rows.
// SWAPPED-OPERAND flash attention: S^T = mfma(K, Q) so each lane owns the
// token axis (softmax axis) for one query column q=l16:
//  - softmax: 31 in-lane ops + 2 shfl_xor (vs 32 bpermutes)
//  - P round-trip: lane's 4 values = 4 consecutive tokens -> packed b64 writes
//    into pT[q][tok] (XOR-swizzled, conflict-free), b128 reads as PV A-frag
//  - V transpose staging XOR-swizzled: 16-way write conflict -> conflict-free
__global__ __launch_bounds__(256) void attn_win(const bf16* __restrict__ qkv,
                                                const bf16* __restrict__ freqs,
                                                bf16* __restrict__ ob) {
  __shared__ unsigned short k8[8 * 128 * 8];  // [dblk][tok][8]  16 KB (roped K)
  __shared__ unsigned short v8[16 * 64 * 8];  // [tokblk][d^swz][8] 16 KB (V^T)
  __shared__ unsigned short pT[4][16 * 128];  // per wave [q:16][tok:128] 4 KB

  const int bid = blockIdx.x;
  const int w = bid & 15, h = (bid >> 4) & 15, b = bid >> 8;
  const int n0 = w * 256;
  const int tid = threadIdx.x;
  const int wave = tid >> 6, lane = tid & 63;
  const int q4 = lane >> 4, l16 = lane & 15;
  const float scale = 0.125f;  // D^-0.5
  const int swz = (l16 & 7) << 4;  // byte XOR for pT (bits 4-6)
  char* const pw = (char*)&pT[wave][0];

  // q fragments with rope, hoisted (B-frag: col=l16=q, k=(q4)*8+e, s picks d-half)
  bf16x8 qf[4][2];
#pragma unroll
  for (int g = 0; g < 4; ++g) {
    const int n = n0 + wave * 64 + g * 16 + l16;
    const bf16* qrow = qkv + (size_t)(b * kN + n) * kQKVN + h * kD;
    const bf16* frow = freqs + (size_t)n * kD;
#pragma unroll
    for (int s = 0; s < 2; ++s) {
      const int d0 = s * 32 + q4 * 8;
      qf[g][s] = rope8(*(const bf16x8*)(qrow + d0), *(const bf16x8*)(frow + d0));
    }
  }

  f32x4 O[4][4] = {};       // [group][d-tile]; rows q=q4*4+r, cols d=l16+16*jd
  float mrow[4], lrow[4];   // per-lane stats for q = g*16 + l16
#pragma unroll
  for (int g = 0; g < 4; ++g) { mrow[g] = -3.0e38f; lrow[g] = 0.0f; }

  for (int c = 0; c < 2; ++c) {
    const int nc = n0 + c * 128;
    __syncthreads();  // previous chunk's reads done before restaging
#pragma unroll
    for (int i = 0; i < 4; ++i) {
      const int cid = i * 256 + tid;
      const int tok = cid & 127, db = cid >> 7;
      const int n = nc + tok;
      const size_t base = (size_t)(b * kN + n) * kQKVN + h * kD + db * 8;
      bf16x8 kv = *(const bf16x8*)(qkv + base + kC);  // K slice
      bf16x8 fv = *(const bf16x8*)(freqs + (size_t)n * kD + db * 8);
      *(bf16x8*)&k8[(db * 128 + tok) * 8] = rope8(kv, fv);
      bf16x8 vv = *(const bf16x8*)(qkv + base + 2 * kC);  // V slice
      const int tb = tok >> 3, sl = tok & 7;
#pragma unroll
      for (int e = 0; e < 8; ++e) {
        const int d = db * 8 + e;
        ((bf16*)v8)[((tb * 64) + (d ^ (tb & 7))) * 8 + sl] = vv[e];
      }
    }
    __syncthreads();

#pragma unroll
    for (int g = 0; g < 4; ++g) {
      // S^T = K Q^T over d=64: lane holds toks {j*16 + q4*4 + r} for q = g*16+l16
      f32x4 S[8] = {};
#pragma unroll
      for (int j = 0; j < 8; ++j)
#pragma unroll
        for (int s = 0; s < 2; ++s) {
          bf16x8 kf = *(const bf16x8*)&k8[((q4 + 4 * s) * 128 + j * 16 + l16) * 8];
          S[j] = MFMA(kf, qf[g][s], S[j]);  // swapped operands
        }
      // scale + in-lane max over 32 tokens (4 parallel chains), then cross-q4
      float m0_ = -3.0e38f, m1_ = -3.0e38f, m2_ = -3.0e38f, m3_ = -3.0e38f;
#pragma unroll
      for (int j = 0; j < 8; ++j) {
        S[j][0] *= scale; S[j][1] *= scale; S[j][2] *= scale; S[j][3] *= scale;
        m0_ = fmaxf(m0_, S[j][0]); m1_ = fmaxf(m1_, S[j][1]);
        m2_ = fmaxf(m2_, S[j][2]); m3_ = fmaxf(m3_, S[j][3]);
      }
      float mx = fmaxf(fmaxf(m0_, m1_), fmaxf(m2_, m3_));
      mx = fmaxf(mx, __shfl_xor(mx, 16));
      mx = fmaxf(mx, __shfl_xor(mx, 32));
      const float mnew = fmaxf(mrow[g], mx);
      const float al = __expf(mrow[g] - mnew);
      mrow[g] = mnew;
      float s0 = 0.f, s1 = 0.f, s2 = 0.f, s3 = 0.f;
#pragma unroll
      for (int j = 0; j < 8; ++j) {
        S[j][0] = __expf(S[j][0] - mnew); s0 += S[j][0];
        S[j][1] = __expf(S[j][1] - mnew); s1 += S[j][1];
        S[j][2] = __expf(S[j][2] - mnew); s2 += S[j][2];
        S[j][3] = __expf(S[j][3] - mnew); s3 += S[j][3];
      }
      float sm = (s0 + s1) + (s2 + s3);
      sm += __shfl_xor(sm, 16);
      sm += __shfl_xor(sm, 32);
      lrow[g] = lrow[g] * al + sm;
      // redistribute alpha to O-row owners (O rows are q = q4*4+r; al lives at lane l16=q)
      float alr[4];
#pragma unroll
      for (int r = 0; r < 4; ++r) alr[r] = __shfl(al, q4 * 4 + r);
#pragma unroll
      for (int jd = 0; jd < 4; ++jd)
#pragma unroll
        for (int r = 0; r < 4; ++r) O[g][jd][r] *= alr[r];
      // P writes: 8 x b64, layout pT[q=l16][tok], swizzled; lane's 4 r = 4 consecutive toks
#pragma unroll
      for (int j = 0; j < 8; ++j) {
        bf16x4 pk = {(bf16)S[j][0], (bf16)S[j][1], (bf16)S[j][2], (bf16)S[j][3]};
        *(bf16x4*)(pw + l16 * 256 + ((j * 32 + q4 * 8) ^ swz)) = pk;
      }
      asm volatile("s_waitcnt lgkmcnt(0)" ::: "memory");  // P writes visible (same wave)
      // O += P V: pf = A-frag [row=q=l16][k=tok=s4*32+q4*8+e] via swizzled b128
#pragma unroll
      for (int s4 = 0; s4 < 4; ++s4) {
        bf16x8 pf = *(const bf16x8*)(pw + l16 * 256 + ((s4 * 64 + q4 * 16) ^ swz));
        const int tb2 = q4 + 4 * s4;
#pragma unroll
        for (int jd = 0; jd < 4; ++jd) {
          const int d2 = (l16 + 16 * jd) ^ (tb2 & 7);
          bf16x8 vf = *(const bf16x8*)&v8[(tb2 * 64 + d2) * 8];
          O[g][jd] = MFMA(pf, vf, O[g][jd]);
        }
      }
      asm volatile("" ::: "memory");  // keep next g's pT writes after this g's reads
    }
  }

  // epilogue: normalize (lrow lives at lane l16=q; O rows are q=q4*4+r), write bf16
#pragma unroll
  for (int g = 0; g < 4; ++g) {
    float lr[4];
#pragma unroll
    for (int r = 0; r < 4; ++r) lr[r] = __shfl(lrow[g], q4 * 4 + r);
    const int nb = n0 + wave * 64 + g * 16 + q4 * 4;
#pragma unroll
    for (int jd = 0; jd < 4; ++jd) {
      const int d = l16 + 16 * jd;
#pragma unroll
      for (int r = 0; r < 4; ++r) {
        const float v = O[g][jd][r] / lr[r];
        ob[(size_t)(b * kN + nb + r) * kC + h * kD + d] = (bf16)v;
      }
    }
  }
}

extern "C" void kernel_launch(void* const* d_in, const int* in_sizes, int n_in,
                              void* d_out, int out_size, void* d_ws, size_t ws_size,
                              hipStream_t stream) {
  (void)in_sizes; (void)n_in; (void)out_size; (void)ws_size;
  const float* x      = (const float*)d_in[0];
  const float* freqs  = (const float*)d_in[1];
  const float* qkv_w  = (const float*)d_in[2];
  const float* proj_w = (const float*)d_in[3];
  const float* proj_b = (const float*)d_in[4];
  float* out = (float*)d_out;

  // workspace layout (bf16 elems):
  //  [qkv_buf: kM*kQKVN][shared: kM*kC (x_bf16 then attn_buf)][qkvw][projw][freqs]
  bf16* qkv_buf = (bf16*)d_ws;
  bf16* shared  = qkv_buf + (size_t)kM * kQKVN;
  bf16* x_b     = shared;                     // live: convert -> gemm1
  bf16* attn_b  = shared;                     // live: attn -> gemm2
  bf16* qkvw_b  = shared + (size_t)kM * kC;
  bf16* projw_b = qkvw_b + (size_t)kQKVN * kC;
  bf16* freqs_b = projw_b + (size_t)kC * kC;

  // fp32 -> bf16 conversions
  cvt_bf16<<<(kM * kC / 4 + 255) / 256, 256, 0, stream>>>(x, x_b, kM * kC / 4);
  cvt_bf16<<<(kQKVN * kC / 4 + 255) / 256, 256, 0, stream>>>(qkv_w, qkvw_b, kQKVN * kC / 4);
  cvt_bf16<<<(kC * kC / 4 + 255) / 256, 256, 0, stream>>>(proj_w, projw_b, kC * kC / 4);
  cvt_bf16<<<(kN * kD / 4 + 255) / 256, 256, 0, stream>>>(freqs, freqs_b, kN * kD / 4);

  gemm_bt<kQKVN, false, bf16><<<dim3(kQKVN / 256, kM / 256), 512, 0, stream>>>(
      x_b, qkvw_b, nullptr, qkv_buf);
  attn_win<<<dim3(kB * kH * (kN / 256)), 256, 0, stream>>>(qkv_buf, freqs_b, attn_b);
  gemm_bt<kC, true, float><<<dim3(kC / 256, kM / 256), 512, 0, stream>>>(
      attn_b, projw_b, proj_b, out);
}